// Round 1
// 368.192 us; speedup vs baseline: 1.0045x; 1.0045x over previous
//
#include <hip/hip_runtime.h>

// RegionIntegrator: B=4, N_REG=225 (15x15 grid, step 32), C=16, RS=64, H=W=512.
// Inverted to a gather: output pixel (y,x) is covered by region-starts
// i in [max(0,(y-32)>>5), min(14, y>>5)] (1 or 2) x same for j -> count in
// {1,2,4}. Traffic floor: 236 MB read (each region elem once) + 67 MB write
// -> ~48 us at 6.3 TB/s.
//
// This version vs previous:
//  - BRANCHLESS: clamped (i0,i1)x(j0,j1) indices are always valid regions, so
//    all loads issue unconditionally (max memory-level parallelism, no exec-
//    mask churn); duplicate loads on border pixels hit the same cache lines
//    (no extra HBM). Adds are masked with selects in the exact reference
//    accumulation order (i-major, j-minor) -> bitwise-identical (x + 0.0f is
//    exact; count division is by a power of two).
//  - 2 ROWS PER THREAD (y and y+256): shares the j-axis math, halves thread
//    count, 8 loads in flight per thread.

constexpr int NREG_DIM = 15;   // 15 starts per axis
constexpr int CH       = 16;
constexpr int RS       = 64;
constexpr int HW       = 512;
constexpr int NREG     = NREG_DIM * NREG_DIM;  // 225

__device__ __forceinline__ float4 f4add(float4 a, float4 b) {
    return make_float4(a.x + b.x, a.y + b.y, a.z + b.z, a.w + b.w);
}
__device__ __forceinline__ float4 f4sel(bool m, float4 v) {
    return m ? v : make_float4(0.f, 0.f, 0.f, 0.f);
}
__device__ __forceinline__ float4 f4scale(float4 a, float s) {
    return make_float4(a.x * s, a.y * s, a.z * s, a.w * s);
}

__global__ __launch_bounds__(256) void region_gather_kernel(
    const float* __restrict__ regions, float* __restrict__ out)
{
    // tid layout: b[2] | c[4] | y0[8] | xq[7]  (xq = x/4, lane-fastest -> coalesced)
    int tid = blockIdx.x * 256 + threadIdx.x;
    int xq = tid & 127;          // x / 4
    int x  = xq << 2;
    int y0 = (tid >> 7) & 255;   // rows 0..255; this thread also does y0+256
    int c  = (tid >> 15) & 15;
    int b  = tid >> 19;
    int y1 = y0 + 256;

    // covering region-start indices (step=32, RS=64), clamped -> always valid
    int j0 = max(0, (x - 32) >> 5);
    int j1 = min(NREG_DIM - 1, x >> 5);
    bool mj = j1 > j0;
    int dx0 = x - (j0 << 5);                 // in [0,63], multiple of 4 -> aligned float4
    int dx1 = x - (j1 << 5);

    int i0a = max(0, (y0 - 32) >> 5);        // y0 < 256 -> no upper clamp needed
    int i1a = y0 >> 5;
    bool mia = i1a > i0a;
    int i0b = (y1 - 32) >> 5;                // y1 >= 256 -> no lower clamp needed
    int i1b = min(NREG_DIM - 1, y1 >> 5);
    bool mib = i1b > i0b;

    const float* base = regions + (size_t)b * (NREG * CH * RS * RS) + (c << 12);
    int dya0 = (y0 - (i0a << 5)) << 6;
    int dya1 = (y0 - (i1a << 5)) << 6;
    int dyb0 = (y1 - (i0b << 5)) << 6;
    int dyb1 = (y1 - (i1b << 5)) << 6;

    // 8 unconditional loads -> all in flight before any accumulate
    const float4 va00 = *(const float4*)(base + ((i0a * NREG_DIM + j0) << 16) + dya0 + dx0);
    const float4 va01 = *(const float4*)(base + ((i0a * NREG_DIM + j1) << 16) + dya0 + dx1);
    const float4 va10 = *(const float4*)(base + ((i1a * NREG_DIM + j0) << 16) + dya1 + dx0);
    const float4 va11 = *(const float4*)(base + ((i1a * NREG_DIM + j1) << 16) + dya1 + dx1);
    const float4 vb00 = *(const float4*)(base + ((i0b * NREG_DIM + j0) << 16) + dyb0 + dx0);
    const float4 vb01 = *(const float4*)(base + ((i0b * NREG_DIM + j1) << 16) + dyb0 + dx1);
    const float4 vb10 = *(const float4*)(base + ((i1b * NREG_DIM + j0) << 16) + dyb1 + dx0);
    const float4 vb11 = *(const float4*)(base + ((i1b * NREG_DIM + j1) << 16) + dyb1 + dx1);

    // accumulate in reference scatter order: (i0,j0),(i0,j1),(i1,j0),(i1,j1)
    float4 acca = va00;
    acca = f4add(acca, f4sel(mj, va01));
    acca = f4add(acca, f4sel(mia, va10));
    acca = f4add(acca, f4sel(mia && mj, va11));
    float4 accb = vb00;
    accb = f4add(accb, f4sel(mj, vb01));
    accb = f4add(accb, f4sel(mib, vb10));
    accb = f4add(accb, f4sel(mib && mj, vb11));

    // count in {1,2,4} -> inverse is an exact power of two
    float inva = 1.0f / (float)(((int)mia + 1) * ((int)mj + 1));
    float invb = 1.0f / (float)(((int)mib + 1) * ((int)mj + 1));

    int o0 = ((((b << 4) + c) << 9) + y0 << 7) + xq;   // float4 index into out
    int o1 = o0 + (256 << 7);
    reinterpret_cast<float4*>(out)[o0] = f4scale(acca, inva);
    reinterpret_cast<float4*>(out)[o1] = f4scale(accb, invb);
}

extern "C" void kernel_launch(void* const* d_in, const int* in_sizes, int n_in,
                              void* d_out, int out_size, void* d_ws, size_t ws_size,
                              hipStream_t stream) {
    const float* regions = (const float*)d_in[0];   // (4,225,16,64,64) f32
    // d_in[1] orig_x: values unused (shape only). d_in[2] positions: regular
    // grid, folded into closed-form index math above. d_in[3..6]: scalars.
    float* out = (float*)d_out;                     // (4,16,512,512) f32

    int total_threads = 4 * CH * (HW / 2) * (HW / 4); // 2,097,152 (2 rows/thread)
    region_gather_kernel<<<total_threads / 256, 256, 0, stream>>>(regions, out);
}